// Round 5
// baseline (76.270 us; speedup 1.0000x reference)
//
#include <hip/hip_runtime.h>

#define HH 1024
#define WW 1024
#define BB 8

typedef float v4f __attribute__((ext_vector_type(4)));

__global__ __launch_bounds__(256) void getaffs_kernel(const float* __restrict__ seg,
                                                      float* __restrict__ out) {
    // XCD-chunked swizzle: round-robin dispatch means bid%8 = XCD, so give XCD x
    // the contiguous row chunk [x*1024,(x+1)*1024) — one 4 MB batch image, which
    // fits its private L2. All shifted-row reads are then L2 hits.
    const int bid = blockIdx.x;
    const int row_id = ((bid & 7) << 10) + (bid >> 3);   // b*HH + i
    const int b = row_id >> 10;
    const int i = row_id & (HH - 1);
    const int j = threadIdx.x << 2;         // columns j..j+3

    const float* srow = seg + (size_t)row_id * WW;
    const v4f c = *reinterpret_cast<const v4f*>(srow + j);

    const size_t plane = (size_t)BB * HH * WW;       // elements per offset plane
    float* op = out + (size_t)row_id * WW + j;       // position inside a plane

    const int ds[4] = {1, 3, 9, 27};

    // Row offsets (-d, 0): output planes 0, 2, 4, 6 — aligned vector loads.
    #pragma unroll
    for (int k = 0; k < 4; ++k) {
        const int d = ds[k];
        v4f r;
        if (i - d >= 0) {
            r = *reinterpret_cast<const v4f*>(seg + ((size_t)b * HH + (i - d)) * WW + j);
        } else {
            r = (v4f){0.f, 0.f, 0.f, 0.f};
        }
        v4f o;
        o.x = (r.x == c.x) ? 1.f : 0.f;
        o.y = (r.y == c.y) ? 1.f : 0.f;
        o.z = (r.z == c.z) ? 1.f : 0.f;
        o.w = (r.w == c.w) ? 1.f : 0.f;
        *reinterpret_cast<v4f*>(op + (size_t)(2 * k) * plane) = o;   // plain store (A/B vs nt)
    }

    // Col offsets (0, -d): output planes 1, 3, 5, 7 — one (unaligned-16B,
    // 4B-aligned) vector load covers cols j-d..j+3-d. Guarded scalar fallback
    // only for the left edge (j < d), i.e. lanes 0..6 of wave 0.
    #pragma unroll
    for (int k = 0; k < 4; ++k) {
        const int d = ds[k];
        v4f o;
        if (j >= d) {
            const v4f s = *reinterpret_cast<const v4f*>(srow + (j - d));
            o.x = (s.x == c.x) ? 1.f : 0.f;
            o.y = (s.y == c.y) ? 1.f : 0.f;
            o.z = (s.z == c.z) ? 1.f : 0.f;
            o.w = (s.w == c.w) ? 1.f : 0.f;
        } else {
            #pragma unroll
            for (int t = 0; t < 4; ++t) {
                const int col = j + t - d;
                const float v = (col >= 0) ? srow[col] : 0.f;
                o[t] = (v == c[t]) ? 1.f : 0.f;
            }
        }
        *reinterpret_cast<v4f*>(op + (size_t)(2 * k + 1) * plane) = o;  // plain store
    }
}

extern "C" void kernel_launch(void* const* d_in, const int* in_sizes, int n_in,
                              void* d_out, int out_size, void* d_ws, size_t ws_size,
                              hipStream_t stream) {
    const float* seg = (const float*)d_in[0];
    float* out = (float*)d_out;
    dim3 grid(BB * HH);
    dim3 block(WW / 4);
    getaffs_kernel<<<grid, block, 0, stream>>>(seg, out);
}

// Round 6
// 57.473 us; speedup vs baseline: 1.3270x; 1.3270x over previous
//
#include <hip/hip_runtime.h>

#define HH 1024
#define WW 1024
#define BB 8

typedef float v4f __attribute__((ext_vector_type(4)));

__global__ __launch_bounds__(256) void getaffs_kernel(const float* __restrict__ seg,
                                                      float* __restrict__ out) {
    // Decomposition: bid&7 = image (= XCD via round-robin dispatch), then
    // plane k (offset index), then row-group of 8 rows. Each block writes ONE
    // 32 KB contiguous range of one output plane (long NT store bursts), and
    // all blocks touching an image sit on the same XCD so row reads L2-hit.
    const int bid = blockIdx.x;
    const int b     = bid & 7;          // image index == XCD
    const int local = bid >> 3;         // 0..1023
    const int k     = local & 7;        // plane 0..7
    const int rg    = local >> 3;       // 0..127 row-group
    const int j = threadIdx.x << 2;     // columns j..j+3

    const int ds[4] = {1, 3, 9, 27};
    const int d = ds[k >> 1];
    const bool is_row_off = (k & 1) == 0;   // even planes: (-d,0); odd: (0,-d)

    const float* img = seg + (size_t)b * HH * WW;
    float* outp = out + (size_t)k * BB * HH * WW + (size_t)b * HH * WW;

    #pragma unroll
    for (int rr = 0; rr < 8; ++rr) {
        const int i = (rg << 3) + rr;
        const float* srow = img + (size_t)i * WW;
        const v4f c = *reinterpret_cast<const v4f*>(srow + j);
        v4f o;
        if (is_row_off) {
            v4f r;
            if (i >= d) {
                r = *reinterpret_cast<const v4f*>(srow - (size_t)d * WW + j);
            } else {
                r = (v4f){0.f, 0.f, 0.f, 0.f};
            }
            o.x = (r.x == c.x) ? 1.f : 0.f;
            o.y = (r.y == c.y) ? 1.f : 0.f;
            o.z = (r.z == c.z) ? 1.f : 0.f;
            o.w = (r.w == c.w) ? 1.f : 0.f;
        } else {
            if (j >= d) {
                const v4f s = *reinterpret_cast<const v4f*>(srow + (j - d));
                o.x = (s.x == c.x) ? 1.f : 0.f;
                o.y = (s.y == c.y) ? 1.f : 0.f;
                o.z = (s.z == c.z) ? 1.f : 0.f;
                o.w = (s.w == c.w) ? 1.f : 0.f;
            } else {
                #pragma unroll
                for (int t = 0; t < 4; ++t) {
                    const int col = j + t - d;
                    const float v = (col >= 0) ? srow[col] : 0.f;
                    o[t] = (v == c[t]) ? 1.f : 0.f;
                }
            }
        }
        __builtin_nontemporal_store(o, reinterpret_cast<v4f*>(outp + (size_t)i * WW + j));
    }
}

extern "C" void kernel_launch(void* const* d_in, const int* in_sizes, int n_in,
                              void* d_out, int out_size, void* d_ws, size_t ws_size,
                              hipStream_t stream) {
    const float* seg = (const float*)d_in[0];
    float* out = (float*)d_out;
    dim3 grid(BB * 8 * (HH / 8));   // 8192: image x plane x row-group
    dim3 block(WW / 4);
    getaffs_kernel<<<grid, block, 0, stream>>>(seg, out);
}